// Round 20
// baseline (105.266 us; speedup 1.0000x reference)
//
#include <hip/hip_runtime.h>
#include <hip/hip_bf16.h>
#include <math.h>

#define B_N   256
#define EMB_N 512
#define CLS_N 20000
#define CLS_PAD 20096
#define NMB   157          // class tiles of 128 (157*128 = 20096)
#define PI_F  3.14159265f
#define F_CONST ((float)(1.1 / 1501.1))

typedef __bf16 bf16x8 __attribute__((ext_vector_type(8)));
typedef float  f32x4  __attribute__((ext_vector_type(4)));

__device__ __forceinline__ unsigned short f2bf(float f) {
    unsigned u = __float_as_uint(f);
    unsigned r = (u + 0x7FFFu + ((u >> 16) & 1u)) >> 16;  // RNE
    return (unsigned short)r;
}

__device__ __forceinline__ void merge4(float& M, float& S, float& VM, int& VI,
                                       float m2, float s2, float vm2, int vi2) {
    float mn = fmaxf(M, m2);
    if (mn == -INFINITY) { S = 0.f; }
    else S = S * __expf(M - mn) + s2 * __expf(m2 - mn);
    M = mn;
    if (vm2 > VM || (vm2 == VM && vi2 < VI)) { VM = vm2; VI = vi2; }
}

// m204 bijective XCD-chunked map for 628 workgroups (628 = 4*79 + 4*78)
__device__ __forceinline__ int map628(int orig) {
    int xcd = orig & 7;
    return (xcd < 4 ? xcd * 79 : 316 + (xcd - 4) * 78) + (orig >> 3);
}

// ---------------- fused convert + prep (one dispatch, R14-verified bytes) ----------------
// blocks 0..627 (m204-matched to gemm): W fp32 [k][c] -> Wt bf16 [c][k] for chunk
//   (tile = wgid>>2, kq = wgid&3). LDS transpose w/ 16B-block XOR permute.
//   colsumsq4[kq][c] plain stores (no memset needed).
// blocks 628..883: per-row scalars + bf16 stacked batch operand; block 628 zeroes accums.
__global__ __launch_bounds__(256) void prep_convert_kernel(
    const float* __restrict__ emb, const int* __restrict__ y,
    const float* __restrict__ W,
    unsigned short* __restrict__ Abf, unsigned short* __restrict__ Wt,
    float* __restrict__ colsumsq4,
    float* __restrict__ xlen_a, float* __restrict__ inv_xlen_a,
    float* __restrict__ inv_wny_a, float* __restrict__ mod_val_a,
    float* __restrict__ accums)
{
    __shared__ alignas(16) unsigned short T[128][136];
    __shared__ float sSq[8][128];
    const int t = threadIdx.x;

    if (blockIdx.x < 628) {
        const int wgid = map628(blockIdx.x);
        const int c0 = (wgid >> 2) * 128;
        const int k0 = (wgid & 3) * 128;
        const int cl = (t & 31) * 4;
        const int kr = t >> 5;                 // 0..7
        const int xp = (t & 7) << 3;           // 16B-block permute key
        float ssq[4] = {0.f, 0.f, 0.f, 0.f};

        #pragma unroll 4
        for (int it = 0; it < 16; ++it) {
            int k = k0 + it * 8 + kr;
            int c = c0 + cl;
            float4 v;
            if (c + 3 < CLS_N) {
                v = *reinterpret_cast<const float4*>(&W[(size_t)k * CLS_N + c]);
            } else {
                v.x = (c + 0 < CLS_N) ? W[(size_t)k * CLS_N + c + 0] : 0.f;
                v.y = (c + 1 < CLS_N) ? W[(size_t)k * CLS_N + c + 1] : 0.f;
                v.z = (c + 2 < CLS_N) ? W[(size_t)k * CLS_N + c + 2] : 0.f;
                v.w = (c + 3 < CLS_N) ? W[(size_t)k * CLS_N + c + 3] : 0.f;
            }
            float vv[4] = {v.x, v.y, v.z, v.w};
            int ki = ((it * 8) ^ xp) + kr;     // permuted k-index (whole 16B blocks)
            #pragma unroll
            for (int j = 0; j < 4; ++j) {
                ssq[j] += vv[j] * vv[j];
                T[cl + j][ki] = f2bf(vv[j]);
            }
        }
        #pragma unroll
        for (int j = 0; j < 4; ++j) sSq[kr][cl + j] = 0.f;
        __syncthreads();
        #pragma unroll
        for (int j = 0; j < 4; ++j) atomicAdd(&sSq[kr][cl + j], ssq[j]);
        __syncthreads();
        if (t < 128) {
            float s = 0.f;
            #pragma unroll
            for (int g = 0; g < 8; ++g) s += sSq[g][t];
            colsumsq4[(size_t)(wgid & 3) * CLS_PAD + c0 + t] = s;
        }
        for (int p = 0; p < 8; ++p) {
            int c  = p * 16 + (t >> 4);
            int xr = ((c >> 2) & 7) << 3;
            uint4 d = *reinterpret_cast<const uint4*>(&T[c][((t & 15) * 8) ^ xr]);
            *reinterpret_cast<uint4*>(&Wt[(size_t)(c0 + c) * EMB_N + k0 + (t & 15) * 8]) = d;
        }
    } else {
        float* r0 = (float*)T;
        float* r1 = r0 + 256;
        float* r2 = r0 + 512;
        const int b = blockIdx.x - 628;
        if (b == 0 && t < 4) accums[t] = 0.f;   // ce, acc, inter, counter
        const int yb = y[b];
        const float* erow = emb + (size_t)b * EMB_N;
        float se = 0.f, sw = 0.f, dt = 0.f;
        for (int e = t; e < EMB_N; e += 256) {
            float ev = erow[e];
            float wv = W[(size_t)e * CLS_N + yb];
            Abf[(size_t)b * EMB_N + e]         = f2bf(ev);
            Abf[(size_t)(B_N + b) * EMB_N + e] = f2bf(wv);
            se += ev * ev; sw += wv * wv; dt += ev * wv;
        }
        r0[t] = se; r1[t] = sw; r2[t] = dt;
        __syncthreads();
        for (int s = 128; s > 0; s >>= 1) {
            if (t < s) { r0[t] += r0[t + s]; r1[t] += r1[t + s]; r2[t] += r2[t + s]; }
            __syncthreads();
        }
        if (t == 0) {
            float xlen = sqrtf(r0[0]);
            float wn   = sqrtf(r1[0]);
            float inv_x = 1.f / xlen;
            float inv_w = 1.f / wn;
            float cos_t = r2[0] * inv_w * inv_x;
            cos_t = fminf(1.f, fmaxf(-1.f, cos_t));
            float c2 = cos_t * cos_t;
            float cos_m = 8.f * c2 * c2 - 8.f * c2 + 1.f;
            float theta = acosf(cos_t);
            float k = floorf(4.f * theta / PI_F);
            float sgn = 1.f - 2.f * fmodf(k, 2.f);
            float phi = sgn * cos_m - 2.f * k;
            float cos_s = cos_t * xlen;
            float phi_s = phi * xlen;
            xlen_a[b] = xlen;
            inv_xlen_a[b] = inv_x;
            inv_wny_a[b] = inv_w;
            mod_val_a[b] = cos_s + F_CONST * (phi_s - cos_s);
        }
    }
}

// ---------------- BARRIER-FREE MFMA GEMM: register-direct fragments ----------------
// 628 blocks (m204, XCD-matched to convert) x 512 threads (8 waves).
// Block = 128 classes x 128 batch; wave = 32 classes x 64 batch (acc[2][4]).
// Per K-step: 2 A-frag + 4 B-frag contiguous 16B/lane global loads + 8 MFMA.
// NO LDS in the loop, NO barriers, NO manual waitcnt — compiler pipelines freely,
// ~20 waves/CU of TLP hide all load latency.
__global__ __launch_bounds__(512) void mfma_gemm_kernel(
    const unsigned short* __restrict__ Wt, const unsigned short* __restrict__ Abf,
    const float* __restrict__ colsumsq4, const int* __restrict__ y,
    const float* __restrict__ xlen_a, const float* __restrict__ inv_xlen_a,
    const float* __restrict__ inv_wny_a,
    float* __restrict__ logits, float4* __restrict__ partials,
    float* __restrict__ inter_sum)
{
    __shared__ float  sIwc[128];
    __shared__ float4 sPart[128][4];
    __shared__ float  red[512];

    const int wgid = map628(blockIdx.x);
    const int tile  = wgid >> 2;
    const int slice = wgid & 3;          // 0,1: logits; 2,3: MHE
    const int m0    = tile * 128;
    const int gn0   = slice * 128;

    const int t    = threadIdx.x;
    const int lane = t & 63;
    const int wid  = t >> 6;             // 0..7
    const int wcl  = wid >> 1;           // class group (0..3) -> 32 classes
    const int wbh  = wid & 1;            // batch half (0..1) -> 64 batch
    const int cl16 = lane & 15;
    const int k8   = lane >> 4;          // 0..3 (k-octet)

    f32x4 acc[2][4] = {};

    // per-lane fragment base pointers (16B contiguous loads)
    const unsigned short* Ap = Wt  + (size_t)(m0 + wcl * 32 + cl16) * EMB_N + k8 * 8;
    const unsigned short* Bp = Abf + (size_t)(gn0 + wbh * 64 + cl16) * EMB_N + k8 * 8;

    #pragma unroll 4
    for (int ks = 0; ks < 16; ++ks) {
        const int kb = ks * 32;
        bf16x8 af[2], bfr[4];
        #pragma unroll
        for (int f = 0; f < 2; ++f)
            af[f] = *reinterpret_cast<const bf16x8*>(Ap + (size_t)f * 16 * EMB_N + kb);
        #pragma unroll
        for (int ni = 0; ni < 4; ++ni)
            bfr[ni] = *reinterpret_cast<const bf16x8*>(Bp + (size_t)ni * 16 * EMB_N + kb);
        #pragma unroll
        for (int f = 0; f < 2; ++f)
            #pragma unroll
            for (int ni = 0; ni < 4; ++ni)
                acc[f][ni] = __builtin_amdgcn_mfma_f32_16x16x32_bf16(
                    af[f], bfr[ni], acc[f][ni], 0, 0, 0);
    }

    // ---- per-class inverse norms from the 4 kq-planes ----
    if (t < 128) {
        int c = m0 + t;
        float s = colsumsq4[c] + colsumsq4[CLS_PAD + c]
                + colsumsq4[2 * CLS_PAD + c] + colsumsq4[3 * CLS_PAD + c];
        sIwc[t] = rsqrtf(fmaxf(s, 1e-30f));
    }
    __syncthreads();

    // thread's classes: local = wcl*32 + f*16 + k8*4 + r
    float iwc[2][4];
    #pragma unroll
    for (int f = 0; f < 2; ++f)
        #pragma unroll
        for (int r = 0; r < 4; ++r)
            iwc[f][r] = sIwc[wcl * 32 + f * 16 + k8 * 4 + r];

    if (slice < 2) {
        // ---- logits + fused per-thread softmax/argmax ----
        #pragma unroll
        for (int ni = 0; ni < 4; ++ni) {
            int bl = wbh * 64 + ni * 16 + cl16;   // 0..127
            int b  = gn0 + bl;                    // 0..255
            float xl  = xlen_a[b];
            float ixl = inv_xlen_a[b];
            float M = -INFINITY, S = 0.f, VM = -INFINITY; int VI = 0x7fffffff;
            #pragma unroll
            for (int f = 0; f < 2; ++f) {
                int cb = m0 + wcl * 32 + f * 16 + k8 * 4;
                if (cb < CLS_N) {            // quad-aligned boundary: fully valid
                    f32x4 vout;
                    #pragma unroll
                    for (int r = 0; r < 4; ++r) {
                        float cosv = acc[f][ni][r] * iwc[f][r] * ixl;
                        cosv = fminf(1.f, fmaxf(-1.f, cosv));
                        float v = cosv * xl;
                        vout[r] = v;
                        if (v > M) { S = S * __expf(M - v) + 1.f; M = v; }
                        else       { S += __expf(v - M); }
                        if (v > VM) { VM = v; VI = cb + r; }
                    }
                    *reinterpret_cast<f32x4*>(&logits[(size_t)b * CLS_N + cb]) = vout;
                }
            }
            // merge across k8 groups (lanes l, l^16, l^32, l^48)
            #pragma unroll
            for (int d = 16; d < 64; d <<= 1) {
                float m2  = __shfl_xor(M, d);
                float s2  = __shfl_xor(S, d);
                float vm2 = __shfl_xor(VM, d);
                int   vi2 = __shfl_xor(VI, d);
                merge4(M, S, VM, VI, m2, s2, vm2, vi2);
            }
            if (k8 == 0) sPart[bl][wcl] = make_float4(M, S, VM, __int_as_float(VI));
        }
        __syncthreads();
        if (t < 128) {
            float4 p0 = sPart[t][0];
            float M = p0.x, S = p0.y, VM = p0.z; int VI = __float_as_int(p0.w);
            #pragma unroll
            for (int g = 1; g < 4; ++g) {
                float4 p = sPart[t][g];
                merge4(M, S, VM, VI, p.x, p.y, p.z, __float_as_int(p.w));
            }
            partials[(size_t)(gn0 + t) * NMB + tile] =
                make_float4(M, S, VM, __int_as_float(VI));
        }
    } else {
        // ---- MHE inter-class term ----
        float part = 0.f;
        #pragma unroll
        for (int ni = 0; ni < 4; ++ni) {
            int b = (slice - 2) * 128 + wbh * 64 + ni * 16 + cl16;   // 0..255
            float iwy = inv_wny_a[b];
            int   yb  = y[b];
            #pragma unroll
            for (int f = 0; f < 2; ++f) {
                int cb = m0 + wcl * 32 + f * 16 + k8 * 4;
                #pragma unroll
                for (int r = 0; r < 4; ++r) {
                    int c = cb + r;
                    if (c < CLS_N && c != yb) {
                        float cww = acc[f][ni][r] * iwc[f][r] * iwy;
                        float d2 = fmaxf(2.f - 2.f * cww, 0.f);
                        part += 1.f / d2;
                    }
                }
            }
        }
        red[t] = part;
        __syncthreads();
        for (int s = 256; s > 0; s >>= 1) {
            if (t < s) red[t] += red[t + s];
            __syncthreads();
        }
        if (t == 0) atomicAdd(inter_sum, red[0]);
    }
}

// ---------------- reduce + finalize (last-block election, R14-verified) ----------------
__global__ __launch_bounds__(64) void reduce_kernel(
    const float4* __restrict__ partials, const float* __restrict__ logits,
    const int* __restrict__ y, const float* __restrict__ mod_val_a,
    float* __restrict__ accums, float* __restrict__ out)
{
    const int b = blockIdx.x;
    const int t = threadIdx.x;
    float M = -INFINITY, S = 0.f, VM = -INFINITY; int VI = 0x7fffffff;
    for (int i = t; i < NMB; i += 64) {
        float4 p = partials[(size_t)b * NMB + i];
        merge4(M, S, VM, VI, p.x, p.y, p.z, __float_as_int(p.w));
    }
    #pragma unroll
    for (int d = 1; d < 64; d <<= 1) {
        float m2  = __shfl_xor(M, d);
        float s2  = __shfl_xor(S, d);
        float vm2 = __shfl_xor(VM, d);
        int   vi2 = __shfl_xor(VI, d);
        merge4(M, S, VM, VI, m2, s2, vm2, vi2);
    }
    if (t == 0) {
        int   yb  = y[b];
        float vyb = logits[(size_t)b * CLS_N + yb];
        float mv  = mod_val_a[b];
        float m2 = fmaxf(M, mv);
        float s2 = S * __expf(M - m2) - __expf(vyb - m2) + __expf(mv - m2);
        float lse = m2 + logf(s2);
        atomicAdd(&accums[0], -(mv - lse));
        if (VI == yb) atomicAdd(&accums[1], 1.f);
        __threadfence();
        int old = atomicAdd((int*)&accums[3], 1);
        if (old == B_N - 1) {
            float ce    = atomicAdd(&accums[0], 0.f) / (float)B_N;
            float acc   = atomicAdd(&accums[1], 0.f) / (float)B_N;
            float inter = atomicAdd(&accums[2], 0.f) / (float)((double)B_N * (CLS_N - 1));
            out[0] = ce + 0.01f * inter;
            out[(size_t)1 + (size_t)B_N * CLS_N + 0] = acc;
            out[(size_t)1 + (size_t)B_N * CLS_N + 1] = inter;
        }
    }
}

extern "C" void kernel_launch(void* const* d_in, const int* in_sizes, int n_in,
                              void* d_out, int out_size, void* d_ws, size_t ws_size,
                              hipStream_t stream) {
    const float* emb = (const float*)d_in[0];
    const int*   y   = (const int*)d_in[1];
    const float* W   = (const float*)d_in[2];
    float* out = (float*)d_out;
    float* logits = out + 1;   // [loss, logits(256x20000), acc, inter]

    // ws layout (bytes)
    const size_t ABF_OFF  = 0;                                        // 524288
    const size_t WT_OFF   = 524288;                                   // 20096*512*2
    const size_t CS_OFF   = WT_OFF + (size_t)CLS_PAD * EMB_N * 2;     // 4 planes
    const size_t PART_OFF = CS_OFF + (size_t)4 * CLS_PAD * 4;         // 256*157*16
    const size_t SC_OFF   = PART_OFF + (size_t)B_N * NMB * 16;

    unsigned short* Abf = (unsigned short*)((char*)d_ws + ABF_OFF);
    unsigned short* Wt  = (unsigned short*)((char*)d_ws + WT_OFF);
    float*  colsumsq4  = (float*)((char*)d_ws + CS_OFF);
    float4* partials   = (float4*)((char*)d_ws + PART_OFF);
    float*  xlen_a     = (float*)((char*)d_ws + SC_OFF);
    float*  inv_xlen_a = xlen_a + 256;
    float*  inv_wny_a  = xlen_a + 512;
    float*  mod_val_a  = xlen_a + 768;
    float*  accums     = xlen_a + 1024;   // ce, acc, inter, counter

    prep_convert_kernel<<<884, 256, 0, stream>>>(emb, y, W, Abf, Wt, colsumsq4,
                                                 xlen_a, inv_xlen_a, inv_wny_a,
                                                 mod_val_a, accums);
    mfma_gemm_kernel<<<628, 512, 0, stream>>>(Wt, Abf, colsumsq4, y,
                                              xlen_a, inv_xlen_a, inv_wny_a,
                                              logits, partials, accums + 2);
    reduce_kernel<<<B_N, 64, 0, stream>>>(partials, logits, y, mod_val_a,
                                          accums, out);
}

// Round 21
// 65.473 us; speedup vs baseline: 1.6078x; 1.6078x over previous
//
#include <hip/hip_runtime.h>
#include <hip/hip_bf16.h>
#include <math.h>

#define B_N   256
#define EMB_N 512
#define CLS_N 20000
#define NMB   157          // class tiles of 128 (157*128 = 20096)
#define PI_F  3.14159265f
#define F_CONST ((float)(1.1 / 1501.1))

typedef __bf16 bf16x8 __attribute__((ext_vector_type(8)));
typedef float  f32x4  __attribute__((ext_vector_type(4)));
typedef unsigned short u16x4 __attribute__((ext_vector_type(4)));

__device__ __forceinline__ unsigned short f2bf(float f) {
    unsigned u = __float_as_uint(f);
    unsigned r = (u + 0x7FFFu + ((u >> 16) & 1u)) >> 16;  // RNE
    return (unsigned short)r;
}

__device__ __forceinline__ void merge4(float& M, float& S, float& VM, int& VI,
                                       float m2, float s2, float vm2, int vi2) {
    float mn = fmaxf(M, m2);
    if (mn == -INFINITY) { S = 0.f; }
    else S = S * __expf(M - mn) + s2 * __expf(m2 - mn);
    M = mn;
    if (vm2 > VM || (vm2 == VM && vi2 < VI)) { VM = vm2; VI = vi2; }
}

// bijective XCD-chunked map for 314 workgroups: 314 = 2*40 + 6*39
__device__ __forceinline__ int map314(int orig) {
    int xcd = orig & 7;
    return (xcd < 2 ? xcd * 40 : 80 + (xcd - 2) * 39) + (orig >> 3);
}

// ---------------- prep: per-row scalars + bf16 stacked batch operand ----------------
__global__ __launch_bounds__(256) void prep_kernel(
    const float* __restrict__ emb, const int* __restrict__ y,
    const float* __restrict__ W,
    unsigned short* __restrict__ Abf,
    float* __restrict__ xlen_a, float* __restrict__ inv_xlen_a,
    float* __restrict__ inv_wny_a, float* __restrict__ mod_val_a,
    float* __restrict__ accums)
{
    const int b = blockIdx.x;
    const int t = threadIdx.x;
    if (b == 0 && t < 4) accums[t] = 0.f;   // ce, acc, inter, counter
    const int yb = y[b];
    const float* erow = emb + (size_t)b * EMB_N;
    float se = 0.f, sw = 0.f, dt = 0.f;
    for (int e = t; e < EMB_N; e += 256) {
        float ev = erow[e];
        float wv = W[(size_t)e * CLS_N + yb];
        Abf[(size_t)b * EMB_N + e]         = f2bf(ev);
        Abf[(size_t)(B_N + b) * EMB_N + e] = f2bf(wv);
        se += ev * ev; sw += wv * wv; dt += ev * wv;
    }
    __shared__ float r0[256], r1[256], r2[256];
    r0[t] = se; r1[t] = sw; r2[t] = dt;
    __syncthreads();
    for (int s = 128; s > 0; s >>= 1) {
        if (t < s) { r0[t] += r0[t + s]; r1[t] += r1[t + s]; r2[t] += r2[t + s]; }
        __syncthreads();
    }
    if (t == 0) {
        float xlen = sqrtf(r0[0]);
        float wn   = sqrtf(r1[0]);
        float inv_x = 1.f / xlen;
        float inv_w = 1.f / wn;
        float cos_t = r2[0] * inv_w * inv_x;
        cos_t = fminf(1.f, fmaxf(-1.f, cos_t));
        float c2 = cos_t * cos_t;
        float cos_m = 8.f * c2 * c2 - 8.f * c2 + 1.f;
        float theta = acosf(cos_t);
        float k = floorf(4.f * theta / PI_F);
        float sgn = 1.f - 2.f * fmodf(k, 2.f);
        float phi = sgn * cos_m - 2.f * k;
        float cos_s = cos_t * xlen;
        float phi_s = phi * xlen;
        xlen_a[b] = xlen;
        inv_xlen_a[b] = inv_x;
        inv_wny_a[b] = inv_w;
        mod_val_a[b] = cos_s + F_CONST * (phi_s - cos_s);
    }
}

// ---------------- fused MFMA GEMM: 128c x 256b tiles, 314 blocks, 512 threads ----------
// Halves W-fp32 redundancy vs R18 (each chunk read 2x not 4x): ~162 MB total load-path.
// A: W fp32 -> reg (1 step ahead) -> bf16 LDS (80B rows, dbuf) + in-kernel sumsq.
// B: global_load_lds (2/thread) dbuf. BK=32, 16 steps, counted vmcnt(6), two fenced
// barriers/step (B-dbuf hazard), setprio on MFMA cluster.
__global__ __launch_bounds__(512, 2) void mfma_gemm_kernel(
    const float* __restrict__ W, const unsigned short* __restrict__ Abf,
    const int* __restrict__ y,
    const float* __restrict__ xlen_a, const float* __restrict__ inv_xlen_a,
    const float* __restrict__ inv_wny_a,
    float* __restrict__ logits, float4* __restrict__ partials,
    float* __restrict__ inter_sum)
{
    __shared__ alignas(16) char smem[53248];   // sA dbuf 2x10240 | sB dbuf 2x16384
    // epilogue overlays (staging dead after loop)
    float*  sSq   = (float*)smem;                 // [8][128] = 4 KB
    float*  sIwc  = (float*)(smem + 4096);        // 128 floats
    float4* sPart = (float4*)(smem + 4608);       // [256][2] = 8 KB
    float*  red   = (float*)(smem + 12800);       // 512 floats

    const int wgid = map314(blockIdx.x);
    const int tile  = wgid >> 1;
    const int slice = wgid & 1;          // 0: logits (emb rows); 1: MHE (Wg rows)
    const int m0    = tile * 128;
    const int gn0   = slice * 256;

    const int t    = threadIdx.x;
    const int lane = t & 63;
    const int wid  = t >> 6;             // 0..7
    const int wr   = wid >> 2;           // class half (64 rows)
    const int wb   = wid & 3;            // batch quarter (64 cols)
    const int r16  = lane & 15;
    const int kh   = lane >> 4;

    const char* Bb = (const char*)Abf;

    f32x4 acc[4][4] = {};
    float2 aq[2][4];
    float ssq0 = 0.f, ssq1 = 0.f;

    // A staging: thread = class pair (c2, c2+1), k-quad ko (4 k's per step)
    const int c2 = (t & 63) * 2;
    const int ko = t >> 6;               // 0..7
    const int gc = min(m0 + c2, CLS_N - 2);

    // B staging map (pre-swizzled source, linear LDS dest)
    const int srow = lane >> 2;
    const int srcq = (lane & 3) ^ ((lane >> 2) & 3);

    #define ISSUE_A(kt, s)                                                        \
        { _Pragma("unroll")                                                       \
          for (int p = 0; p < 4; ++p)                                             \
              aq[s][p] = *reinterpret_cast<const float2*>(                        \
                  &W[(size_t)((kt) + ko * 4 + p) * CLS_N + gc]);                  \
        }

    #define ISSUE_B(kt, buf)                                                      \
        { _Pragma("unroll")                                                       \
          for (int i = 0; i < 2; ++i) {                                           \
              int slot = wid * 2 + i;                                             \
              int row  = slot * 16 + srow;                                        \
              __builtin_amdgcn_global_load_lds(                                   \
                  (const __attribute__((address_space(1))) unsigned int*)         \
                      (Bb + (size_t)(gn0 + row) * 1024 + (size_t)(kt) * 2         \
                          + srcq * 16),                                           \
                  (__attribute__((address_space(3))) unsigned int*)               \
                      (smem + 20480 + (buf) * 16384 + slot * 1024),               \
                  16, 0, 0);                                                      \
          } }

    #define WRITE_A(s, buf)                                                       \
        { u16x4 u0, u1; float s0 = 0.f, s1 = 0.f;                                 \
          _Pragma("unroll")                                                       \
          for (int p = 0; p < 4; ++p) {                                           \
              float vx = aq[s][p].x, vy = aq[s][p].y;                             \
              u0[p] = f2bf(vx); u1[p] = f2bf(vy);                                 \
              s0 += vx * vx; s1 += vy * vy;                                       \
          }                                                                       \
          ssq0 += s0; ssq1 += s1;                                                 \
          *reinterpret_cast<u16x4*>(smem + (buf) * 10240 + c2 * 80 + ko * 8) = u0; \
          *reinterpret_cast<u16x4*>(smem + (buf) * 10240 + (c2 + 1) * 80 + ko * 8) = u1; }

    #define COMPUTE(buf)                                                          \
        { bf16x8 af[4], bfr[4];                                                   \
          _Pragma("unroll")                                                       \
          for (int mi = 0; mi < 4; ++mi) {                                        \
              int row = wr * 64 + mi * 16 + r16;                                  \
              af[mi] = *reinterpret_cast<const bf16x8*>(                          \
                  smem + (buf) * 10240 + row * 80 + kh * 16);                     \
          }                                                                       \
          _Pragma("unroll")                                                       \
          for (int ni = 0; ni < 4; ++ni) {                                        \
              int rowb = wb * 64 + ni * 16 + r16;                                 \
              bfr[ni] = *reinterpret_cast<const bf16x8*>(                         \
                  smem + 20480 + (buf) * 16384 + rowb * 64                        \
                  + ((kh ^ (rowb & 3)) << 4));                                    \
          }                                                                       \
          __builtin_amdgcn_s_setprio(1);                                          \
          _Pragma("unroll")                                                       \
          for (int mi = 0; mi < 4; ++mi)                                          \
              _Pragma("unroll")                                                   \
              for (int ni = 0; ni < 4; ++ni)                                      \
                  acc[mi][ni] = __builtin_amdgcn_mfma_f32_16x16x32_bf16(          \
                      af[mi], bfr[ni], acc[mi][ni], 0, 0, 0);                     \
          __builtin_amdgcn_s_setprio(0); }

    #define FENCE() __builtin_amdgcn_sched_barrier(0);

    ISSUE_A(0, 0)  ISSUE_B(0, 0)

    #pragma unroll
    for (int tt = 0; tt < 16; ++tt) {
        WRITE_A(tt & 1, tt & 1)          // implicit wait covers only aq[tt&1]
        if (tt < 15) {
            ISSUE_A((tt + 1) * 32, (tt + 1) & 1)
            ISSUE_B((tt + 1) * 32, (tt + 1) & 1)
            FENCE()
            // outstanding: B(tt)2 A(tt+1)4 B(tt+1)2 = 8 -> retire B(tt) only
            asm volatile("s_waitcnt vmcnt(6) lgkmcnt(0)" ::: "memory");
        } else {
            FENCE()
            asm volatile("s_waitcnt vmcnt(0) lgkmcnt(0)" ::: "memory");
        }
        FENCE()
        asm volatile("s_barrier" ::: "memory");
        FENCE()
        COMPUTE(tt & 1)
        FENCE()
        asm volatile("s_barrier" ::: "memory");   // B-dbuf write hazard
        FENCE()
    }
    #undef ISSUE_A
    #undef ISSUE_B
    #undef WRITE_A
    #undef COMPUTE
    #undef FENCE

    __syncthreads();   // drain; smem becomes epilogue overlay

    // ---- per-class inverse norms (8 k-quad partials per class) ----
    sSq[ko * 128 + c2]     = ssq0;
    sSq[ko * 128 + c2 + 1] = ssq1;
    __syncthreads();
    if (t < 128) {
        float s = 0.f;
        #pragma unroll
        for (int g = 0; g < 8; ++g) s += sSq[g * 128 + t];
        sIwc[t] = rsqrtf(s);
    }
    __syncthreads();

    float iwc[4][4];
    #pragma unroll
    for (int mi = 0; mi < 4; ++mi)
        #pragma unroll
        for (int r = 0; r < 4; ++r)
            iwc[mi][r] = sIwc[wr * 64 + mi * 16 + kh * 4 + r];

    if (slice == 0) {
        // ---- logits + fused per-thread softmax/argmax (all 256 batch rows) ----
        #pragma unroll
        for (int ni = 0; ni < 4; ++ni) {
            int b = wb * 64 + ni * 16 + r16;    // 0..255
            float xl  = xlen_a[b];
            float ixl = inv_xlen_a[b];
            float M = -INFINITY, S = 0.f, VM = -INFINITY; int VI = 0x7fffffff;
            #pragma unroll
            for (int mi = 0; mi < 4; ++mi) {
                int cb = m0 + wr * 64 + mi * 16 + kh * 4;
                if (cb < CLS_N) {            // quad-aligned boundary: fully valid
                    f32x4 vout;
                    #pragma unroll
                    for (int r = 0; r < 4; ++r) {
                        float cosv = acc[mi][ni][r] * iwc[mi][r] * ixl;
                        cosv = fminf(1.f, fmaxf(-1.f, cosv));
                        float v = cosv * xl;
                        vout[r] = v;
                        if (v > M) { S = S * __expf(M - v) + 1.f; M = v; }
                        else       { S += __expf(v - M); }
                        if (v > VM) { VM = v; VI = cb + r; }
                    }
                    *reinterpret_cast<f32x4*>(&logits[(size_t)b * CLS_N + cb]) = vout;
                }
            }
            // merge across kh groups (lanes l, l^16, l^32, l^48)
            #pragma unroll
            for (int d = 16; d < 64; d <<= 1) {
                float m2  = __shfl_xor(M, d);
                float s2  = __shfl_xor(S, d);
                float vm2 = __shfl_xor(VM, d);
                int   vi2 = __shfl_xor(VI, d);
                merge4(M, S, VM, VI, m2, s2, vm2, vi2);
            }
            if (kh == 0) sPart[b * 2 + wr] = make_float4(M, S, VM, __int_as_float(VI));
        }
        __syncthreads();
        if (t < 256) {
            float4 p0 = sPart[t * 2 + 0], p1 = sPart[t * 2 + 1];
            float M = p0.x, S = p0.y, VM = p0.z; int VI = __float_as_int(p0.w);
            merge4(M, S, VM, VI, p1.x, p1.y, p1.z, __float_as_int(p1.w));
            partials[(size_t)t * NMB + tile] =
                make_float4(M, S, VM, __int_as_float(VI));
        }
    } else {
        // ---- MHE inter-class term (all 256 batch rows) ----
        float part = 0.f;
        #pragma unroll
        for (int ni = 0; ni < 4; ++ni) {
            int b = wb * 64 + ni * 16 + r16;    // 0..255
            float iwy = inv_wny_a[b];
            int   yb  = y[b];
            #pragma unroll
            for (int mi = 0; mi < 4; ++mi) {
                int cb = m0 + wr * 64 + mi * 16 + kh * 4;
                #pragma unroll
                for (int r = 0; r < 4; ++r) {
                    int c = cb + r;
                    if (c < CLS_N && c != yb) {
                        float cww = acc[mi][ni][r] * iwc[mi][r] * iwy;
                        float d2 = fmaxf(2.f - 2.f * cww, 0.f);
                        part += 1.f / d2;
                    }
                }
            }
        }
        red[t] = part;
        __syncthreads();
        for (int s = 256; s > 0; s >>= 1) {
            if (t < s) red[t] += red[t + s];
            __syncthreads();
        }
        if (t == 0) atomicAdd(inter_sum, red[0]);
    }
}

// ---------------- reduce + finalize (last-block election) ----------------
__global__ __launch_bounds__(64) void reduce_kernel(
    const float4* __restrict__ partials, const float* __restrict__ logits,
    const int* __restrict__ y, const float* __restrict__ mod_val_a,
    float* __restrict__ accums, float* __restrict__ out)
{
    const int b = blockIdx.x;
    const int t = threadIdx.x;
    float M = -INFINITY, S = 0.f, VM = -INFINITY; int VI = 0x7fffffff;
    for (int i = t; i < NMB; i += 64) {
        float4 p = partials[(size_t)b * NMB + i];
        merge4(M, S, VM, VI, p.x, p.y, p.z, __float_as_int(p.w));
    }
    #pragma unroll
    for (int d = 1; d < 64; d <<= 1) {
        float m2  = __shfl_xor(M, d);
        float s2  = __shfl_xor(S, d);
        float vm2 = __shfl_xor(VM, d);
        int   vi2 = __shfl_xor(VI, d);
        merge4(M, S, VM, VI, m2, s2, vm2, vi2);
    }
    if (t == 0) {
        int   yb  = y[b];
        float vyb = logits[(size_t)b * CLS_N + yb];
        float mv  = mod_val_a[b];
        float m2 = fmaxf(M, mv);
        float s2 = S * __expf(M - m2) - __expf(vyb - m2) + __expf(mv - m2);
        float lse = m2 + logf(s2);
        atomicAdd(&accums[0], -(mv - lse));
        if (VI == yb) atomicAdd(&accums[1], 1.f);
        __threadfence();
        int old = atomicAdd((int*)&accums[3], 1);
        if (old == B_N - 1) {
            float ce    = atomicAdd(&accums[0], 0.f) / (float)B_N;
            float acc   = atomicAdd(&accums[1], 0.f) / (float)B_N;
            float inter = atomicAdd(&accums[2], 0.f) / (float)((double)B_N * (CLS_N - 1));
            out[0] = ce + 0.01f * inter;
            out[(size_t)1 + (size_t)B_N * CLS_N + 0] = acc;
            out[(size_t)1 + (size_t)B_N * CLS_N + 1] = inter;
        }
    }
}

extern "C" void kernel_launch(void* const* d_in, const int* in_sizes, int n_in,
                              void* d_out, int out_size, void* d_ws, size_t ws_size,
                              hipStream_t stream) {
    const float* emb = (const float*)d_in[0];
    const int*   y   = (const int*)d_in[1];
    const float* W   = (const float*)d_in[2];
    float* out = (float*)d_out;
    float* logits = out + 1;   // [loss, logits(256x20000), acc, inter]

    // ws layout (bytes)
    const size_t ABF_OFF  = 0;                                  // 512*512*2 = 524288
    const size_t PART_OFF = 524288;                             // 256*157*16
    const size_t SC_OFF   = PART_OFF + (size_t)B_N * NMB * 16;

    unsigned short* Abf = (unsigned short*)((char*)d_ws + ABF_OFF);
    float4* partials   = (float4*)((char*)d_ws + PART_OFF);
    float*  xlen_a     = (float*)((char*)d_ws + SC_OFF);
    float*  inv_xlen_a = xlen_a + 256;
    float*  inv_wny_a  = xlen_a + 512;
    float*  mod_val_a  = xlen_a + 768;
    float*  accums     = xlen_a + 1024;   // ce, acc, inter, counter

    prep_kernel<<<B_N, 256, 0, stream>>>(emb, y, W, Abf,
                                         xlen_a, inv_xlen_a, inv_wny_a, mod_val_a,
                                         accums);
    mfma_gemm_kernel<<<314, 512, 0, stream>>>(W, Abf, y,
                                              xlen_a, inv_xlen_a, inv_wny_a,
                                              logits, partials, accums + 2);
    reduce_kernel<<<B_N, 64, 0, stream>>>(partials, logits, y, mod_val_a,
                                          accums, out);
}

// Round 22
// 53.570 us; speedup vs baseline: 1.9650x; 1.2222x over previous
//
#include <hip/hip_runtime.h>
#include <hip/hip_bf16.h>
#include <math.h>

#define B_N   256
#define EMB_N 512
#define CLS_N 20000
#define NMB   157          // class tiles of 128 (157*128 = 20096)
#define PI_F  3.14159265f
#define F_CONST ((float)(1.1 / 1501.1))

typedef __bf16 bf16x8 __attribute__((ext_vector_type(8)));
typedef float  f32x4  __attribute__((ext_vector_type(4)));
typedef unsigned short u16x8 __attribute__((ext_vector_type(8)));

__device__ __forceinline__ unsigned short f2bf(float f) {
    unsigned u = __float_as_uint(f);
    unsigned r = (u + 0x7FFFu + ((u >> 16) & 1u)) >> 16;  // RNE
    return (unsigned short)r;
}

__device__ __forceinline__ void merge4(float& M, float& S, float& VM, int& VI,
                                       float m2, float s2, float vm2, int vi2) {
    float mn = fmaxf(M, m2);
    if (mn == -INFINITY) { S = 0.f; }
    else S = S * __expf(M - mn) + s2 * __expf(m2 - mn);
    M = mn;
    if (vm2 > VM || (vm2 == VM && vi2 < VI)) { VM = vm2; VI = vi2; }
}

// ---------------- prep: per-row scalars + bf16 stacked batch operand ----------------
__global__ __launch_bounds__(256) void prep_kernel(
    const float* __restrict__ emb, const int* __restrict__ y,
    const float* __restrict__ W,
    unsigned short* __restrict__ Abf,
    float* __restrict__ xlen_a, float* __restrict__ inv_xlen_a,
    float* __restrict__ inv_wny_a, float* __restrict__ mod_val_a,
    float* __restrict__ accums)
{
    const int b = blockIdx.x;
    const int t = threadIdx.x;
    if (b == 0 && t < 4) accums[t] = 0.f;   // ce, acc, inter, counter
    const int yb = y[b];
    const float* erow = emb + (size_t)b * EMB_N;
    float se = 0.f, sw = 0.f, dt = 0.f;
    for (int e = t; e < EMB_N; e += 256) {
        float ev = erow[e];
        float wv = W[(size_t)e * CLS_N + yb];
        Abf[(size_t)b * EMB_N + e]         = f2bf(ev);
        Abf[(size_t)(B_N + b) * EMB_N + e] = f2bf(wv);
        se += ev * ev; sw += wv * wv; dt += ev * wv;
    }
    __shared__ float r0[256], r1[256], r2[256];
    r0[t] = se; r1[t] = sw; r2[t] = dt;
    __syncthreads();
    for (int s = 128; s > 0; s >>= 1) {
        if (t < s) { r0[t] += r0[t + s]; r1[t] += r1[t + s]; r2[t] += r2[t + s]; }
        __syncthreads();
    }
    if (t == 0) {
        float xlen = sqrtf(r0[0]);
        float wn   = sqrtf(r1[0]);
        float inv_x = 1.f / xlen;
        float inv_w = 1.f / wn;
        float cos_t = r2[0] * inv_w * inv_x;
        cos_t = fminf(1.f, fmaxf(-1.f, cos_t));
        float c2 = cos_t * cos_t;
        float cos_m = 8.f * c2 * c2 - 8.f * c2 + 1.f;
        float theta = acosf(cos_t);
        float k = floorf(4.f * theta / PI_F);
        float sgn = 1.f - 2.f * fmodf(k, 2.f);
        float phi = sgn * cos_m - 2.f * k;
        float cos_s = cos_t * xlen;
        float phi_s = phi * xlen;
        xlen_a[b] = xlen;
        inv_xlen_a[b] = inv_x;
        inv_wny_a[b] = inv_w;
        mod_val_a[b] = cos_s + F_CONST * (phi_s - cos_s);
    }
}

// ---------------- fused MFMA GEMM (R13-structure: single barrier/step + setprio) -----
// Tile 128 classes x 128 batch; 628 blocks = 157 tiles x 4 slices (m204 XCD map).
// A: W fp32 -> reg (1 step ahead) -> bf16 LDS (80B rows, dbuf) + in-kernel sumsq.
// B: global_load_lds 1 step ahead into 4 slabs. BK=32, 16 steps, vmcnt(10) counted.
__global__ __launch_bounds__(256, 3) void mfma_gemm_kernel(
    const float* __restrict__ W, const unsigned short* __restrict__ Abf,
    const int* __restrict__ y,
    const float* __restrict__ xlen_a, const float* __restrict__ inv_xlen_a,
    const float* __restrict__ inv_wny_a,
    float* __restrict__ logits, float4* __restrict__ partials,
    float* __restrict__ inter_sum)
{
    __shared__ alignas(16) char smem[53248];   // sA dbuf 2x10240 | sB slabs 4x8192
    // epilogue overlays (staging dead after loop)
    float*  sSq   = (float*)smem;                 // [4][128] = 2 KB
    float*  sIwc  = (float*)(smem + 2048);        // 128 floats
    float4* sPart = (float4*)(smem + 2560);       // [128][2] = 4 KB
    float*  red   = (float*)(smem + 6656);        // 256 floats

    // m204 bijective XCD-chunked mapping: 628 = 4*79 + 4*78
    const int orig = blockIdx.x;
    const int xcd  = orig & 7;
    const int wgid = (xcd < 4 ? xcd * 79 : 316 + (xcd - 4) * 78) + (orig >> 3);
    const int tile  = wgid >> 2;
    const int slice = wgid & 3;          // 0,1: logits; 2,3: MHE
    const int m0    = tile * 128;
    const int gn0   = slice * 128;

    const int t    = threadIdx.x;
    const int lane = t & 63;
    const int wid  = t >> 6;
    const int wr   = wid >> 1;           // class half (64 rows)
    const int wc   = wid & 1;            // batch half (64 cols)
    const int r16  = lane & 15;
    const int kh   = lane >> 4;

    const char* Bb = (const char*)Abf;

    f32x4 acc[4][4] = {};
    float2 aq[2][8];
    float ssq0 = 0.f, ssq1 = 0.f;

    // A staging: thread = class pair (c2, c2+1), k-octet ko
    const int c2 = (t & 63) * 2;
    const int ko = t >> 6;
    const int gc = min(m0 + c2, CLS_N - 2);

    // B staging map (pre-swizzled source, linear LDS dest)
    const int srow = lane >> 2;
    const int srcq = (lane & 3) ^ ((lane >> 2) & 3);

    #define ISSUE_A(kt, s)                                                        \
        { _Pragma("unroll")                                                       \
          for (int p = 0; p < 8; ++p)                                             \
              aq[s][p] = *reinterpret_cast<const float2*>(                        \
                  &W[(size_t)((kt) + ko * 8 + p) * CLS_N + gc]);                  \
        }

    #define ISSUE_B(kt, slab)                                                     \
        { _Pragma("unroll")                                                       \
          for (int i = 0; i < 2; ++i) {                                           \
              int slot = wid * 2 + i;                                             \
              int row  = slot * 16 + srow;                                        \
              __builtin_amdgcn_global_load_lds(                                   \
                  (const __attribute__((address_space(1))) unsigned int*)         \
                      (Bb + (size_t)(gn0 + row) * 1024 + (size_t)(kt) * 2         \
                          + srcq * 16),                                           \
                  (__attribute__((address_space(3))) unsigned int*)               \
                      (smem + 20480 + (slab) * 8192 + slot * 1024),               \
                  16, 0, 0);                                                      \
          } }

    #define WRITE_A(s, buf)                                                       \
        { u16x8 u0, u1; float s0 = 0.f, s1 = 0.f;                                 \
          _Pragma("unroll")                                                       \
          for (int p = 0; p < 8; ++p) {                                           \
              float vx = aq[s][p].x, vy = aq[s][p].y;                             \
              u0[p] = f2bf(vx); u1[p] = f2bf(vy);                                 \
              s0 += vx * vx; s1 += vy * vy;                                       \
          }                                                                       \
          ssq0 += s0; ssq1 += s1;                                                 \
          *reinterpret_cast<u16x8*>(smem + (buf) * 10240 + c2 * 80 + ko * 16) = u0; \
          *reinterpret_cast<u16x8*>(smem + (buf) * 10240 + (c2 + 1) * 80 + ko * 16) = u1; }

    #define COMPUTE(buf, slab)                                                    \
        { bf16x8 af[4], bfr[4];                                                   \
          _Pragma("unroll")                                                       \
          for (int mi = 0; mi < 4; ++mi) {                                        \
              int row = wr * 64 + mi * 16 + r16;                                  \
              af[mi] = *reinterpret_cast<const bf16x8*>(                          \
                  smem + (buf) * 10240 + row * 80 + kh * 16);                     \
          }                                                                       \
          _Pragma("unroll")                                                       \
          for (int ni = 0; ni < 4; ++ni) {                                        \
              int rowb = wc * 64 + ni * 16 + r16;                                 \
              bfr[ni] = *reinterpret_cast<const bf16x8*>(                         \
                  smem + 20480 + (slab) * 8192 + rowb * 64                        \
                  + ((kh ^ (rowb & 3)) << 4));                                    \
          }                                                                       \
          __builtin_amdgcn_s_setprio(1);                                          \
          _Pragma("unroll")                                                       \
          for (int mi = 0; mi < 4; ++mi)                                          \
              _Pragma("unroll")                                                   \
              for (int ni = 0; ni < 4; ++ni)                                      \
                  acc[mi][ni] = __builtin_amdgcn_mfma_f32_16x16x32_bf16(          \
                      af[mi], bfr[ni], acc[mi][ni], 0, 0, 0);                     \
          __builtin_amdgcn_s_setprio(0); }

    #define FENCE() __builtin_amdgcn_sched_barrier(0);

    ISSUE_A(0, 0)  ISSUE_B(0, 0)

    #pragma unroll
    for (int tt = 0; tt < 16; ++tt) {
        WRITE_A(tt & 1, tt & 1)          // implicit wait covers only aq[tt&1]
        if (tt < 15) {
            ISSUE_A((tt + 1) * 32, (tt + 1) & 1)
            ISSUE_B((tt + 1) * 32, (tt + 1) & 3)
            FENCE()
            // outstanding: B(tt)2 A(tt+1)8 B(tt+1)2 = 12 -> retire B(tt) only
            asm volatile("s_waitcnt vmcnt(10) lgkmcnt(0)" ::: "memory");
        } else {
            FENCE()
            asm volatile("s_waitcnt vmcnt(0) lgkmcnt(0)" ::: "memory");
        }
        FENCE()
        asm volatile("s_barrier" ::: "memory");
        FENCE()
        COMPUTE(tt & 1, tt & 3)
        FENCE()
        // no second barrier: A-dbuf + B-4slab tolerate 1-step wave drift
    }
    #undef ISSUE_A
    #undef ISSUE_B
    #undef WRITE_A
    #undef COMPUTE
    #undef FENCE

    __syncthreads();   // drain; smem becomes epilogue overlay

    // ---- per-class inverse norms (4 k-octet partials per class) ----
    sSq[ko * 128 + c2]     = ssq0;
    sSq[ko * 128 + c2 + 1] = ssq1;
    __syncthreads();
    if (t < 128) {
        float s = sSq[t] + sSq[128 + t] + sSq[256 + t] + sSq[384 + t];
        sIwc[t] = rsqrtf(s);
    }
    __syncthreads();

    float iwc[4][4];
    #pragma unroll
    for (int mi = 0; mi < 4; ++mi)
        #pragma unroll
        for (int r = 0; r < 4; ++r)
            iwc[mi][r] = sIwc[wr * 64 + mi * 16 + kh * 4 + r];

    if (slice < 2) {
        // ---- logits + fused per-thread softmax/argmax ----
        #pragma unroll
        for (int ni = 0; ni < 4; ++ni) {
            int bl = wc * 64 + ni * 16 + r16;   // 0..127
            int b  = gn0 + bl;                   // 0..255
            float xl  = xlen_a[b];
            float ixl = inv_xlen_a[b];
            float M = -INFINITY, S = 0.f, VM = -INFINITY; int VI = 0x7fffffff;
            #pragma unroll
            for (int mi = 0; mi < 4; ++mi) {
                int cb = m0 + wr * 64 + mi * 16 + kh * 4;
                if (cb < CLS_N) {            // quad-aligned boundary: fully valid
                    f32x4 vout;
                    #pragma unroll
                    for (int r = 0; r < 4; ++r) {
                        float cosv = acc[mi][ni][r] * iwc[mi][r] * ixl;
                        cosv = fminf(1.f, fmaxf(-1.f, cosv));
                        float v = cosv * xl;
                        vout[r] = v;
                        if (v > M) { S = S * __expf(M - v) + 1.f; M = v; }
                        else       { S += __expf(v - M); }
                        if (v > VM) { VM = v; VI = cb + r; }
                    }
                    *reinterpret_cast<f32x4*>(&logits[(size_t)b * CLS_N + cb]) = vout;
                }
            }
            #pragma unroll
            for (int d = 16; d < 64; d <<= 1) {
                float m2  = __shfl_xor(M, d);
                float s2  = __shfl_xor(S, d);
                float vm2 = __shfl_xor(VM, d);
                int   vi2 = __shfl_xor(VI, d);
                merge4(M, S, VM, VI, m2, s2, vm2, vi2);
            }
            if (kh == 0) sPart[bl * 2 + wr] = make_float4(M, S, VM, __int_as_float(VI));
        }
        __syncthreads();
        if (t < 128) {
            float4 p0 = sPart[t * 2 + 0], p1 = sPart[t * 2 + 1];
            float M = p0.x, S = p0.y, VM = p0.z; int VI = __float_as_int(p0.w);
            merge4(M, S, VM, VI, p1.x, p1.y, p1.z, __float_as_int(p1.w));
            partials[(size_t)(gn0 + t) * NMB + tile] =
                make_float4(M, S, VM, __int_as_float(VI));
        }
    } else {
        // ---- MHE inter-class term ----
        float part = 0.f;
        #pragma unroll
        for (int ni = 0; ni < 4; ++ni) {
            int b = (slice - 2) * 128 + wc * 64 + ni * 16 + r16;   // 0..255
            float iwy = inv_wny_a[b];
            int   yb  = y[b];
            #pragma unroll
            for (int mi = 0; mi < 4; ++mi) {
                int cb = m0 + wr * 64 + mi * 16 + kh * 4;
                #pragma unroll
                for (int r = 0; r < 4; ++r) {
                    int c = cb + r;
                    if (c < CLS_N && c != yb) {
                        float cww = acc[mi][ni][r] * iwc[mi][r] * iwy;
                        float d2 = fmaxf(2.f - 2.f * cww, 0.f);
                        part += 1.f / d2;
                    }
                }
            }
        }
        red[t] = part;
        __syncthreads();
        for (int s = 128; s > 0; s >>= 1) {
            if (t < s) red[t] += red[t + s];
            __syncthreads();
        }
        if (t == 0) atomicAdd(inter_sum, red[0]);
    }
}

// ---------------- reduce + finalize (last-block election) ----------------
__global__ __launch_bounds__(64) void reduce_kernel(
    const float4* __restrict__ partials, const float* __restrict__ logits,
    const int* __restrict__ y, const float* __restrict__ mod_val_a,
    float* __restrict__ accums, float* __restrict__ out)
{
    const int b = blockIdx.x;
    const int t = threadIdx.x;
    float M = -INFINITY, S = 0.f, VM = -INFINITY; int VI = 0x7fffffff;
    for (int i = t; i < NMB; i += 64) {
        float4 p = partials[(size_t)b * NMB + i];
        merge4(M, S, VM, VI, p.x, p.y, p.z, __float_as_int(p.w));
    }
    #pragma unroll
    for (int d = 1; d < 64; d <<= 1) {
        float m2  = __shfl_xor(M, d);
        float s2  = __shfl_xor(S, d);
        float vm2 = __shfl_xor(VM, d);
        int   vi2 = __shfl_xor(VI, d);
        merge4(M, S, VM, VI, m2, s2, vm2, vi2);
    }
    if (t == 0) {
        int   yb  = y[b];
        float vyb = logits[(size_t)b * CLS_N + yb];
        float mv  = mod_val_a[b];
        float m2 = fmaxf(M, mv);
        float s2 = S * __expf(M - m2) - __expf(vyb - m2) + __expf(mv - m2);
        float lse = m2 + logf(s2);
        atomicAdd(&accums[0], -(mv - lse));
        if (VI == yb) atomicAdd(&accums[1], 1.f);
        __threadfence();
        int old = atomicAdd((int*)&accums[3], 1);
        if (old == B_N - 1) {
            float ce    = atomicAdd(&accums[0], 0.f) / (float)B_N;
            float acc   = atomicAdd(&accums[1], 0.f) / (float)B_N;
            float inter = atomicAdd(&accums[2], 0.f) / (float)((double)B_N * (CLS_N - 1));
            out[0] = ce + 0.01f * inter;
            out[(size_t)1 + (size_t)B_N * CLS_N + 0] = acc;
            out[(size_t)1 + (size_t)B_N * CLS_N + 1] = inter;
        }
    }
}

extern "C" void kernel_launch(void* const* d_in, const int* in_sizes, int n_in,
                              void* d_out, int out_size, void* d_ws, size_t ws_size,
                              hipStream_t stream) {
    const float* emb = (const float*)d_in[0];
    const int*   y   = (const int*)d_in[1];
    const float* W   = (const float*)d_in[2];
    float* out = (float*)d_out;
    float* logits = out + 1;   // [loss, logits(256x20000), acc, inter]

    // ws layout (bytes)
    const size_t ABF_OFF  = 0;                                  // 512*512*2 = 524288
    const size_t PART_OFF = 524288;                             // 256*157*16
    const size_t SC_OFF   = PART_OFF + (size_t)B_N * NMB * 16;

    unsigned short* Abf = (unsigned short*)((char*)d_ws + ABF_OFF);
    float4* partials   = (float4*)((char*)d_ws + PART_OFF);
    float*  xlen_a     = (float*)((char*)d_ws + SC_OFF);
    float*  inv_xlen_a = xlen_a + 256;
    float*  inv_wny_a  = xlen_a + 512;
    float*  mod_val_a  = xlen_a + 768;
    float*  accums     = xlen_a + 1024;   // ce, acc, inter, counter

    prep_kernel<<<B_N, 256, 0, stream>>>(emb, y, W, Abf,
                                         xlen_a, inv_xlen_a, inv_wny_a, mod_val_a,
                                         accums);
    mfma_gemm_kernel<<<628, 256, 0, stream>>>(W, Abf, y,
                                              xlen_a, inv_xlen_a, inv_wny_a,
                                              logits, partials, accums + 2);
    reduce_kernel<<<B_N, 64, 0, stream>>>(partials, logits, y, mod_val_a,
                                          accums, out);
}